// Round 5
// baseline (91.378 us; speedup 1.0000x reference)
//
#include <hip/hip_runtime.h>
#include <hip/hip_fp16.h>
#include <math.h>

#define B_N   2
#define A_N   180
#define HR_N  512
#define H_OUT 512
#define W_OUT 512
#define PAD   51               // int(0.1 * 512)
#define HP    614              // H_OUT + 2*PAD
#define WP    614
#define GUARD 80               // zero guard each side
#define HPP   (HP + 2*GUARD)   // 774
#define NPIX  (H_OUT * W_OUT)

#define TILE  16               // 16x16 pixel tiles, 256 threads
#define CH    30               // angles per LDS chunk
#define NCH   (A_N / CH)       // 6
#define WIN   24               // window entries per angle per tile

// Workspace:
//   pk2[A_N][HPP] uint2: {half2(b0[y],b1[y]), half2(b0[y+1],b1[y+1])}, zero-guarded
//   tg[A_N] float2: {cos, sin}

__device__ __forceinline__ float col_val(const float* __restrict__ sino,
                                         int b, int a, int yy) {
    if (yy < 0 || yy >= HP) return 0.0f;
    float src = ((float)yy + 0.5f) * ((float)HR_N / (float)HP) - 0.5f;
    src = fminf(fmaxf(src, 0.0f), (float)(HR_N - 1));
    int i0 = (int)floorf(src);
    int i1 = min(i0 + 1, HR_N - 1);
    float wH = src - (float)i0;
    const float* srow = sino + ((size_t)b * A_N + a) * HR_N;
    return srow[i0] * (1.0f - wH) + srow[i1] * wH;
}

__global__ void prep_kernel(const float* __restrict__ sino,
                            const float* __restrict__ angles,
                            uint2* __restrict__ pk2,
                            float2* __restrict__ tg) {
    int idx = blockIdx.x * blockDim.x + threadIdx.x;
    if (idx < A_N) {
        float th = -angles[idx] * (float)(M_PI / 180.0);
        tg[idx] = make_float2(cosf(th), sinf(th));
    }
    const int total = A_N * HPP;
    if (idx < total) {
        int y = idx % HPP;
        int a = idx / HPP;
        int yy = y - GUARD;
        float v00 = col_val(sino, 0, a, yy);
        float v10 = col_val(sino, 1, a, yy);
        float v01 = col_val(sino, 0, a, yy + 1);
        float v11 = col_val(sino, 1, a, yy + 1);
        __half2 lo = __floats2half2_rn(v00, v10);
        __half2 hi = __floats2half2_rn(v01, v11);
        uint2 u;
        u.x = *(unsigned int*)&lo;
        u.y = *(unsigned int*)&hi;
        pk2[idx] = u;
    }
}

template <bool INTERIOR>
__device__ __forceinline__ void bp_body(const uint2* __restrict__ pk2,
                                        const float2* __restrict__ tgv,
                                        uint2* __restrict__ s_win,
                                        const int* __restrict__ s_base,
                                        int t, float X, float Y, float Xc, float Yc,
                                        float& acc0, float& acc1) {
    for (int ch = 0; ch < NCH; ++ch) {
        int a0 = ch * CH;
        // Stage CH angle-windows (contiguous WIN-entry runs) into LDS
        for (int e = t; e < CH * WIN; e += 256) {
            int la = e / WIN;
            int j  = e - la * WIN;
            int a  = a0 + la;
            s_win[e] = pk2[(size_t)a * HPP + (GUARD + s_base[a] + j)];
        }
        __syncthreads();

#pragma unroll 6
        for (int la = 0; la < CH; ++la) {
            float2 cs = tgv[a0 + la];          // uniform index -> s_load
            float c = cs.x, s = cs.y;
            float iyc   = fmaf(s, Xc, fmaf(c, Yc, 306.5f));
            float basef = floorf(iyc);          // == (float)(s_base[a]+11)
            float iyp   = fmaf(s, X, fmaf(c, Y, 317.5f));   // iy + 11
            float f  = iyp - basef;             // in (0.39, 22.61)
            int   li = (int)f;
            float wy = f - (float)li;

            uint2 cv = s_win[la * WIN + li];    // ds_read_b64, imm offset la*192
            __half2 lo = *(__half2*)&cv.x;
            __half2 hi = *(__half2*)&cv.y;
            float c00 = __low2float(lo), c10 = __high2float(lo);
            float c01 = __low2float(hi), c11 = __high2float(hi);

            if (INTERIOR) {
                acc0 = fmaf(wy, c01 - c00, acc0 + c00);
                acc1 = fmaf(wy, c11 - c10, acc1 + c10);
            } else {
                float ix = fmaf(c, X, fmaf(-s, Y, 306.5f));
                float xf = fminf(fmaxf(ix + 1.0f, 0.0f), 1.0f)
                         * fminf(fmaxf((float)WP - ix, 0.0f), 1.0f);
                float t0 = fmaf(wy, c01 - c00, c00);
                float t1 = fmaf(wy, c11 - c10, c10);
                acc0 = fmaf(xf, t0, acc0);
                acc1 = fmaf(xf, t1, acc1);
            }
        }
        __syncthreads();
    }
}

__global__ __launch_bounds__(256) void bp_kernel(const uint2* __restrict__ pk2,
                                                 const float2* __restrict__ tgv,
                                                 float* __restrict__ out) {
    __shared__ uint2 s_win[CH * WIN];
    __shared__ int   s_base[A_N];

    int t  = threadIdx.x;
    int tx = blockIdx.x, ty = blockIdx.y;
    float Xc = (float)(tx * TILE) - 248.0f;    // tile-center coords
    float Yc = (float)(ty * TILE) - 248.0f;

    if (t < A_N) {
        float2 cs = tgv[t];
        float iyc = fmaf(cs.y, Xc, fmaf(cs.x, Yc, 306.5f));
        s_base[t] = (int)floorf(iyc) - 11;     // window covers [base, base+23]
    }

    int lx = t & (TILE - 1);
    int ly = t >> 4;
    float X = (float)(tx * TILE + lx) - 255.5f;
    float Y = (float)(ty * TILE + ly) - 255.5f;

    float acc0 = 0.0f, acc1 = 0.0f;
    __syncthreads();

    // Interior tiles: every pixel has ix in [0,613] for all angles -> xfac == 1
    bool interior = (Xc * Xc + Yc * Yc) <= 87500.0f;   // rc <= ~295.8
    if (interior)
        bp_body<true >(pk2, tgv, s_win, s_base, t, X, Y, Xc, Yc, acc0, acc1);
    else
        bp_body<false>(pk2, tgv, s_win, s_base, t, X, Y, Xc, Yc, acc0, acc1);

    const float inv = 1.0f / (180.0f + 1e-6f);
    int idx = (ty * TILE + ly) * W_OUT + (tx * TILE + lx);
    out[idx]        = acc0 * inv;
    out[NPIX + idx] = acc1 * inv;
}

extern "C" void kernel_launch(void* const* d_in, const int* in_sizes, int n_in,
                              void* d_out, int out_size, void* d_ws, size_t ws_size,
                              hipStream_t stream) {
    const float* sino   = (const float*)d_in[0];
    const float* angles = (const float*)d_in[1];
    char*   ws  = (char*)d_ws;
    uint2*  pk2 = (uint2*)ws;                              // A_N * HPP * 8 B
    float2* tg  = (float2*)(ws + (size_t)A_N * HPP * sizeof(uint2));

    const int total = A_N * HPP;
    prep_kernel<<<(total + 255) / 256, 256, 0, stream>>>(sino, angles, pk2, tg);

    dim3 grid(W_OUT / TILE, H_OUT / TILE);                 // 32 x 32 tiles
    bp_kernel<<<grid, 256, 0, stream>>>(pk2, tg, (float*)d_out);
}

// Round 6
// 86.003 us; speedup vs baseline: 1.0625x; 1.0625x over previous
//
#include <hip/hip_runtime.h>
#include <hip/hip_fp16.h>
#include <math.h>

#define B_N   2
#define A_N   180
#define HR_N  512
#define H_OUT 512
#define W_OUT 512
#define PAD   51               // int(0.1 * 512)
#define HP    614              // H_OUT + 2*PAD
#define WP    614
#define GUARD 80               // zero guard each side
#define HPP   (HP + 2*GUARD)   // 774
#define NPIX  (H_OUT * W_OUT)

#define TILE   16              // 16x16 pixel tiles, 256 threads
#define HALF_A 90              // angles per block (2-way angle split)
#define CH     30              // angles per LDS chunk
#define NCHH   (HALF_A / CH)   // 3
#define WIN    24              // window entries per angle per tile

// Workspace:
//   pk2[A_N][HPP] uint2: {half2(b0[y],b1[y]), half2(b0[y+1],b1[y+1])}, zero-guarded
//   tg[A_N] float2: {cos, sin}

__device__ __forceinline__ float col_val(const float* __restrict__ sino,
                                         int b, int a, int yy) {
    if (yy < 0 || yy >= HP) return 0.0f;
    float src = ((float)yy + 0.5f) * ((float)HR_N / (float)HP) - 0.5f;
    src = fminf(fmaxf(src, 0.0f), (float)(HR_N - 1));
    int i0 = (int)floorf(src);
    int i1 = min(i0 + 1, HR_N - 1);
    float wH = src - (float)i0;
    const float* srow = sino + ((size_t)b * A_N + a) * HR_N;
    return srow[i0] * (1.0f - wH) + srow[i1] * wH;
}

__global__ void prep_kernel(const float* __restrict__ sino,
                            const float* __restrict__ angles,
                            uint2* __restrict__ pk2,
                            float2* __restrict__ tg) {
    int idx = blockIdx.x * blockDim.x + threadIdx.x;
    if (idx < A_N) {
        float th = -angles[idx] * (float)(M_PI / 180.0);
        tg[idx] = make_float2(cosf(th), sinf(th));
    }
    const int total = A_N * HPP;
    if (idx < total) {
        int y = idx % HPP;
        int a = idx / HPP;
        int yy = y - GUARD;
        float v00 = col_val(sino, 0, a, yy);
        float v10 = col_val(sino, 1, a, yy);
        float v01 = col_val(sino, 0, a, yy + 1);
        float v11 = col_val(sino, 1, a, yy + 1);
        __half2 lo = __floats2half2_rn(v00, v10);
        __half2 hi = __floats2half2_rn(v01, v11);
        uint2 u;
        u.x = *(unsigned int*)&lo;
        u.y = *(unsigned int*)&hi;
        pk2[idx] = u;
    }
}

template <bool INTERIOR>
__device__ __forceinline__ void bp_body(const uint2* __restrict__ pkh,
                                        const float4* __restrict__ s_ang,
                                        const int* __restrict__ s_base,
                                        uint2* __restrict__ s_win,
                                        int t, float X, float Y,
                                        float& acc0, float& acc1) {
    for (int ch = 0; ch < NCHH; ++ch) {
        int a0 = ch * CH;
        // Stage CH angle-windows (contiguous WIN-entry runs) into LDS
        for (int e = t; e < CH * WIN; e += 256) {
            int la = e / WIN;
            int j  = e - la * WIN;
            int a  = a0 + la;
            s_win[e] = pkh[(size_t)a * HPP + (GUARD + s_base[a] + j)];
        }
        __syncthreads();

#pragma unroll 6
        for (int la = 0; la < CH; ++la) {
            float4 ang = s_ang[a0 + la];        // one broadcast ds_read_b128
            float c = ang.x, s = ang.y, fb = ang.z;
            float iy = fmaf(s, X, fmaf(c, Y, 306.5f));
            float f  = iy - fb;                 // in (0.39, 22.61)
            int   li = (int)f;
            float wy = f - (float)li;

            uint2 cv = s_win[la * WIN + li];    // ds_read_b64
            __half2 lo = *(__half2*)&cv.x;
            __half2 hi = *(__half2*)&cv.y;
            float c00 = __low2float(lo), c10 = __high2float(lo);
            float c01 = __low2float(hi), c11 = __high2float(hi);

            if (INTERIOR) {
                acc0 = fmaf(wy, c01 - c00, acc0 + c00);
                acc1 = fmaf(wy, c11 - c10, acc1 + c10);
            } else {
                float ix = fmaf(c, X, fmaf(-s, Y, 306.5f));
                float xf = fminf(fmaxf(ix + 1.0f, 0.0f), 1.0f)
                         * fminf(fmaxf((float)WP - ix, 0.0f), 1.0f);
                acc0 = fmaf(xf, fmaf(wy, c01 - c00, c00), acc0);
                acc1 = fmaf(xf, fmaf(wy, c11 - c10, c10), acc1);
            }
        }
        __syncthreads();
    }
}

__global__ __launch_bounds__(256) void bp_kernel(const uint2* __restrict__ pk2,
                                                 const float2* __restrict__ tgv,
                                                 float* __restrict__ out) {
    __shared__ float4 s_ang[HALF_A];   // {c, s, (float)base, 0}
    __shared__ int    s_base[HALF_A];
    __shared__ uint2  s_win[CH * WIN];

    int t    = threadIdx.x;
    int tx   = blockIdx.x & 31, ty = blockIdx.x >> 5;
    int half = blockIdx.y;
    float Xc = (float)(tx * TILE) - 248.0f;    // tile-center coords
    float Yc = (float)(ty * TILE) - 248.0f;

    if (t < HALF_A) {
        float2 cs = tgv[half * HALF_A + t];
        float iyc = fmaf(cs.y, Xc, fmaf(cs.x, Yc, 306.5f));
        int base = (int)floorf(iyc) - 11;      // window covers [base, base+23]
        s_ang[t]  = make_float4(cs.x, cs.y, (float)base, 0.0f);
        s_base[t] = base;
    }

    int lx = t & (TILE - 1);
    int ly = t >> 4;
    float X = (float)(tx * TILE + lx) - 255.5f;
    float Y = (float)(ty * TILE + ly) - 255.5f;

    float acc0 = 0.0f, acc1 = 0.0f;
    __syncthreads();

    const uint2* pkh = pk2 + (size_t)(half * HALF_A) * HPP;

    // Interior tiles: ix in [0,613] for every pixel & angle -> xfac == 1
    bool interior = (Xc * Xc + Yc * Yc) <= 87500.0f;
    if (interior)
        bp_body<true >(pkh, s_ang, s_base, s_win, t, X, Y, acc0, acc1);
    else
        bp_body<false>(pkh, s_ang, s_base, s_win, t, X, Y, acc0, acc1);

    const float inv = 1.0f / (180.0f + 1e-6f);
    int idx = (ty * TILE + ly) * W_OUT + (tx * TILE + lx);
    atomicAdd(&out[idx],        acc0 * inv);
    atomicAdd(&out[NPIX + idx], acc1 * inv);
}

extern "C" void kernel_launch(void* const* d_in, const int* in_sizes, int n_in,
                              void* d_out, int out_size, void* d_ws, size_t ws_size,
                              hipStream_t stream) {
    const float* sino   = (const float*)d_in[0];
    const float* angles = (const float*)d_in[1];
    char*   ws  = (char*)d_ws;
    uint2*  pk2 = (uint2*)ws;                              // A_N * HPP * 8 B
    float2* tg  = (float2*)(ws + (size_t)A_N * HPP * sizeof(uint2));

    const int total = A_N * HPP;
    prep_kernel<<<(total + 255) / 256, 256, 0, stream>>>(sino, angles, pk2, tg);

    hipMemsetAsync(d_out, 0, (size_t)out_size * sizeof(float), stream);

    dim3 grid(1024, 2);                                    // 32x32 tiles x 2 angle-halves
    bp_kernel<<<grid, 256, 0, stream>>>(pk2, tg, (float*)d_out);
}

// Round 8
// 84.668 us; speedup vs baseline: 1.0792x; 1.0158x over previous
//
#include <hip/hip_runtime.h>
#include <hip/hip_fp16.h>
#include <math.h>

#define B_N   2
#define A_N   180
#define HR_N  512
#define H_OUT 512
#define W_OUT 512
#define PAD   51               // int(0.1 * 512)
#define HP    614              // H_OUT + 2*PAD
#define WP    614
#define GUARD 80               // zero guard each side
#define HPP   (HP + 2*GUARD)   // 774
#define NPIX  (H_OUT * W_OUT)

#define TW     16              // tile width (pixels)
#define TH     8               // tile height (pixels) -> 128 px, 256 thr (2 angle halves)
#define HALF_A 90
#define CH     30              // angles per LDS chunk (per half)
#define NCH    (HALF_A / CH)   // 3
#define WIN    20              // window entries per angle per tile (span <= 18.3)

// Workspace:
//   pk2[A_N][HPP] uint2: {half2(b0[y],b1[y]), half2(b0[y+1],b1[y+1])}, zero-guarded
//   tg[A_N] float2: {cos, sin}

__device__ __forceinline__ float col_val(const float* __restrict__ sino,
                                         int b, int a, int yy) {
    if (yy < 0 || yy >= HP) return 0.0f;
    float src = ((float)yy + 0.5f) * ((float)HR_N / (float)HP) - 0.5f;
    src = fminf(fmaxf(src, 0.0f), (float)(HR_N - 1));
    int i0 = (int)floorf(src);
    int i1 = min(i0 + 1, HR_N - 1);
    float wH = src - (float)i0;
    const float* srow = sino + ((size_t)b * A_N + a) * HR_N;
    return srow[i0] * (1.0f - wH) + srow[i1] * wH;
}

__global__ void prep_kernel(const float* __restrict__ sino,
                            const float* __restrict__ angles,
                            uint2* __restrict__ pk2,
                            float2* __restrict__ tg) {
    int idx = blockIdx.x * blockDim.x + threadIdx.x;
    if (idx < A_N) {
        float th = -angles[idx] * (float)(M_PI / 180.0);
        tg[idx] = make_float2(cosf(th), sinf(th));
    }
    const int total = A_N * HPP;
    if (idx < total) {
        int y = idx % HPP;
        int a = idx / HPP;
        int yy = y - GUARD;
        float v00 = col_val(sino, 0, a, yy);
        float v10 = col_val(sino, 1, a, yy);
        float v01 = col_val(sino, 0, a, yy + 1);
        float v11 = col_val(sino, 1, a, yy + 1);
        __half2 lo = __floats2half2_rn(v00, v10);
        __half2 hi = __floats2half2_rn(v01, v11);
        uint2 u;
        u.x = *(unsigned int*)&lo;
        u.y = *(unsigned int*)&hi;
        pk2[idx] = u;
    }
}

__global__ __launch_bounds__(256, 8) void bp_kernel(const uint2* __restrict__ pk2,
                                                    const float2* __restrict__ tgv,
                                                    float* __restrict__ out) {
    __shared__ float4 s_ang[A_N];          // {c, s, K = 306.5 - base, 0}
    __shared__ int    s_base[A_N];
    __shared__ uint2  s_win[2 * CH * WIN]; // [half][la][j]
    __shared__ float  s_red[2][128];

    int t  = threadIdx.x;
    int tx = blockIdx.x, ty = blockIdx.y;
    float Xc = (float)(tx * TW) - 248.0f;   // tile-center X (= +7.5 - 255.5)
    float Yc = (float)(ty * TH) - 252.0f;   // tile-center Y (= +3.5 - 255.5)

    if (t < A_N) {
        float2 cs = tgv[t];
        float iyc = fmaf(cs.y, Xc, fmaf(cs.x, Yc, 306.5f));
        int base = (int)floorf(iyc) - 9;    // window covers [base, base+19]
        s_ang[t]  = make_float4(cs.x, cs.y, 306.5f - (float)base, 0.0f);
        s_base[t] = base;
    }

    int half = t >> 7;                      // waves 0-1: angles 0-89; waves 2-3: 90-179
    int tt   = t & 127;
    int lx = tt & (TW - 1), ly = tt >> 4;
    float X = (float)(tx * TW + lx) - 255.5f;
    float Y = (float)(ty * TH + ly) - 255.5f;

    float acc0 = 0.0f, acc1 = 0.0f;
    __syncthreads();

    // Interior tiles: ix in [0,613] for every pixel & angle -> xfac == 1
    bool interior = (Xc * Xc + Yc * Yc) <= 87500.0f;

    for (int ch = 0; ch < NCH; ++ch) {
        // Stage CH angle-windows for BOTH halves into LDS
        for (int e = t; e < 2 * CH * WIN; e += 256) {
            int hh = e / (CH * WIN);
            int r  = e - hh * (CH * WIN);
            int la = r / WIN;
            int j  = r - la * WIN;
            int a  = hh * HALF_A + ch * CH + la;
            s_win[e] = pk2[(size_t)a * HPP + (GUARD + s_base[a] + j)];
        }
        __syncthreads();

        const int aoff = half * HALF_A + ch * CH;
        const int woff = half * (CH * WIN);
        if (interior) {
#pragma unroll 5
            for (int la = 0; la < CH; ++la) {
                float4 ang = s_ang[aoff + la];              // broadcast b128
                float f  = fmaf(ang.y, X, fmaf(ang.x, Y, ang.z));  // in (0.7, 18.3)
                int   li = (int)f;
                float wy = f - (float)li;
                uint2 cv = s_win[woff + la * WIN + li];     // ds_read_b64
                __half2 lo = *(__half2*)&cv.x;
                __half2 hi = *(__half2*)&cv.y;
                __half2 d  = __hsub2(hi, lo);
                __half2 wv = __float2half2_rn(wy);
                __half2 r2 = __hfma2(wv, d, lo);
                acc0 += __low2float(r2);
                acc1 += __high2float(r2);
            }
        } else {
#pragma unroll 5
            for (int la = 0; la < CH; ++la) {
                float4 ang = s_ang[aoff + la];
                float f  = fmaf(ang.y, X, fmaf(ang.x, Y, ang.z));
                int   li = (int)f;
                float wy = f - (float)li;
                uint2 cv = s_win[woff + la * WIN + li];
                __half2 lo = *(__half2*)&cv.x;
                __half2 hi = *(__half2*)&cv.y;
                __half2 d  = __hsub2(hi, lo);
                __half2 wv = __float2half2_rn(wy);
                __half2 r2 = __hfma2(wv, d, lo);
                float ix = fmaf(ang.x, X, fmaf(-ang.y, Y, 306.5f));
                float xf = fminf(fmaxf(ix + 1.0f, 0.0f), 1.0f)
                         * fminf(fmaxf((float)WP - ix, 0.0f), 1.0f);
                acc0 = fmaf(xf, __low2float(r2), acc0);
                acc1 = fmaf(xf, __high2float(r2), acc1);
            }
        }
        __syncthreads();
    }

    // Combine the two angle halves (no atomics, no global memset)
    if (half) {
        s_red[0][tt] = acc0;
        s_red[1][tt] = acc1;
    }
    __syncthreads();
    if (!half) {
        const float inv = 1.0f / (180.0f + 1e-6f);
        float a0 = (acc0 + s_red[0][tt]) * inv;
        float a1 = (acc1 + s_red[1][tt]) * inv;
        int idx = (ty * TH + ly) * W_OUT + (tx * TW + lx);
        out[idx]        = a0;
        out[NPIX + idx] = a1;
    }
}

extern "C" void kernel_launch(void* const* d_in, const int* in_sizes, int n_in,
                              void* d_out, int out_size, void* d_ws, size_t ws_size,
                              hipStream_t stream) {
    const float* sino   = (const float*)d_in[0];
    const float* angles = (const float*)d_in[1];
    char*   ws  = (char*)d_ws;
    uint2*  pk2 = (uint2*)ws;                              // A_N * HPP * 8 B
    float2* tg  = (float2*)(ws + (size_t)A_N * HPP * sizeof(uint2));

    const int total = A_N * HPP;
    prep_kernel<<<(total + 255) / 256, 256, 0, stream>>>(sino, angles, pk2, tg);

    dim3 grid(W_OUT / TW, H_OUT / TH);                     // 32 x 64 = 2048 blocks
    bp_kernel<<<grid, 256, 0, stream>>>(pk2, tg, (float*)d_out);
}